// Round 20
// baseline (181.587 us; speedup 1.0000x reference)
//
#include <hip/hip_runtime.h>

// FirNeXtV2 DDSP synth. Numerics certified r13-r19 (absmax 0.0078125).
// Perf v8: k_out rebuilt as R=8 single-wave blocks with XOR-swizzled LDS
// coefficient windows (conflict-free b128 at stride 32B) and wave-uniform
// (SMEM) global source loads. All 5 segments unified to c0 = 512-j0 local
// form with zero-padded windows. k_mix keeps the r17 structure (40 us).

#define BLKS  512
#define WL    2048
#define W4    512
#define NB    4
#define NFR   512
#define LTOT  (NFR*BLKS)     // 262144
#define NCH   (LTOT/16)      // 16384
#define SN_LEN 260096        // WL*127

typedef float f4 __attribute__((ext_vector_type(4)));

// Swizzled LDS f4 read: f4-slot s = w ^ ((w>>3)&1); 8 consecutive lanes at
// w-stride 2 hit all 8 bank-quads -> conflict-free b128.
static __device__ __forceinline__ f4 ldswz(const float* __restrict__ W, int fi) {
    int w = fi >> 2;
    return ((const f4*)W)[w ^ ((w >> 3) & 1)];
}

// R=8 x 4-tap segment; coefficient window W (swizzled LDS, zero-padded),
// source S wave-uniform global (SMEM). Per-accumulator taps ascend in m.
static __device__ __forceinline__ void seg8s(const float* __restrict__ W, int c0,
                                             const float* __restrict__ S,
                                             float&a0,float&a1,float&a2,float&a3,
                                             float&a4,float&a5,float&a6,float&a7) {
    f4 A = ldswz(W, c0 - 8);
    f4 B = ldswz(W, c0 - 4);
    #pragma unroll 4
    for (int m0 = 0; m0 < 512; m0 += 4) {
        f4 C = ldswz(W, c0 + m0);
        f4 x = *(const f4*)(S + m0);           // uniform address -> s_load
        a0 += C.x*x.x; a0 += C.y*x.y; a0 += C.z*x.z; a0 += C.w*x.w;
        a1 += B.w*x.x; a1 += C.x*x.y; a1 += C.y*x.z; a1 += C.z*x.w;
        a2 += B.z*x.x; a2 += B.w*x.y; a2 += C.x*x.z; a2 += C.y*x.w;
        a3 += B.y*x.x; a3 += B.z*x.y; a3 += B.w*x.z; a3 += C.x*x.w;
        a4 += B.x*x.x; a4 += B.y*x.y; a4 += B.z*x.z; a4 += B.w*x.w;
        a5 += A.w*x.x; a5 += B.x*x.y; a5 += B.y*x.z; a5 += B.z*x.w;
        a6 += A.z*x.x; a6 += A.w*x.y; a6 += B.x*x.z; a6 += B.y*x.w;
        a7 += A.y*x.x; a7 += A.z*x.y; a7 += A.w*x.z; a7 += B.x*x.w;
        A = B; B = C;
    }
}

// Paired harmonic+noise segment (k_mix), r17 structure.
static __device__ __forceinline__ void segmix(const float* __restrict__ Ph,
                                              const float* __restrict__ Pn, int c0,
                                              const float* __restrict__ Sh,
                                              const float* __restrict__ Sn,
                                              float&a0,float&a1,float&a2,float&a3) {
    f4 Ah = *(const f4*)(Ph + c0 - 4);
    f4 An = *(const f4*)(Pn + c0 - 4);
    #pragma unroll 4
    for (int m0 = 0; m0 < 512; m0 += 4) {
        f4 Bh = *(const f4*)(Ph + c0 + m0);
        f4 Bn = *(const f4*)(Pn + c0 + m0);
        f4 xh = *(const f4*)(Sh + m0);
        f4 xr = *(const f4*)(Sn + m0);
        f4 xn; xn.x = xr.x*0.3162f; xn.y = xr.y*0.3162f;
               xn.z = xr.z*0.3162f; xn.w = xr.w*0.3162f;
        a0 += Bh.x*xh.x; a0 += Bn.x*xn.x;  a0 += Bh.y*xh.y; a0 += Bn.y*xn.y;
        a0 += Bh.z*xh.z; a0 += Bn.z*xn.z;  a0 += Bh.w*xh.w; a0 += Bn.w*xn.w;
        a1 += Ah.w*xh.x; a1 += An.w*xn.x;  a1 += Bh.x*xh.y; a1 += Bn.x*xn.y;
        a1 += Bh.y*xh.z; a1 += Bn.y*xn.z;  a1 += Bh.z*xh.w; a1 += Bn.z*xn.w;
        a2 += Ah.z*xh.x; a2 += An.z*xn.x;  a2 += Ah.w*xh.y; a2 += An.w*xn.y;
        a2 += Bh.x*xh.z; a2 += Bn.x*xn.z;  a2 += Bh.y*xh.w; a2 += Bn.y*xn.w;
        a3 += Ah.y*xh.x; a3 += An.y*xn.x;  a3 += Ah.z*xh.y; a3 += An.z*xn.y;
        a3 += Ah.w*xh.z; a3 += An.w*xn.z;  a3 += Bh.x*xh.w; a3 += Bn.x*xn.w;
        Ah = Bh; An = Bn;
    }
}

// ---------------------------------------------------------------------------
__global__ void __launch_bounds__(256) k_scan_a(const float* __restrict__ f0_frames,
                                                float* __restrict__ L0,
                                                float* __restrict__ L1) {
    int b = blockIdx.y;
    int chunk = blockIdx.x * 256 + threadIdx.x;
    int g0 = chunk * 16;
    float d = f0_frames[b*NFR + (g0 >> 9)] / 44100.0f;
    float* o = L0 + (size_t)b*LTOT + g0;
    float acc = 0.0f;
    #pragma unroll
    for (int j = 0; j < 16; ++j) { acc = acc + d; o[j] = acc; }
    L1[(size_t)b*NCH + chunk] = acc;
}

__global__ void __launch_bounds__(1024) k_scan_b(float* __restrict__ L1g) {
    __shared__ float sL2[1024];
    __shared__ float sL3[64];
    __shared__ float sL4[4];
    int b = blockIdx.x, tid = threadIdx.x;
    float* L1 = L1g + (size_t)b*NCH;
    {
        float* p = L1 + tid*16;
        float acc = 0.0f;
        #pragma unroll
        for (int j = 0; j < 16; ++j) { acc = acc + p[j]; p[j] = acc; }
        sL2[tid] = acc;
    }
    __syncthreads();
    if (tid < 64) {
        float acc = 0.0f;
        #pragma unroll
        for (int j = 0; j < 16; ++j) { acc = acc + sL2[tid*16+j]; sL2[tid*16+j] = acc; }
        sL3[tid] = acc;
    }
    __syncthreads();
    if (tid < 4) {
        float acc = 0.0f;
        #pragma unroll
        for (int j = 0; j < 16; ++j) { acc = acc + sL3[tid*16+j]; sL3[tid*16+j] = acc; }
        sL4[tid] = acc;
    }
    __syncthreads();
    if (tid == 0) {
        float acc = 0.0f;
        #pragma unroll
        for (int j = 0; j < 4; ++j) { acc = acc + sL4[j]; sL4[j] = acc; }
    }
    __syncthreads();
    if (tid >= 16 && tid < 64) sL3[tid] = sL3[tid] + sL4[tid/16 - 1];
    __syncthreads();
    if (tid >= 16) sL2[tid] = sL2[tid] + sL3[tid/16 - 1];
    __syncthreads();
    for (int i = tid; i < NCH; i += 1024)
        if (i >= 16) L1[i] = L1[i] + sL2[i/16 - 1];
}

__global__ void __launch_bounds__(256) k_source(const float* __restrict__ f0_frames,
                                                const float* __restrict__ L0,
                                                const float* __restrict__ L1,
                                                float* __restrict__ hs) {
    int F = blockIdx.x, b = blockIdx.y;
    int tid = threadIdx.x;
    float f0 = f0_frames[b*NFR + F];
    float af = rintf(44100.0f / fmaxf(f0, 20.0f) * 0.5f) * 2.0f + 1.0f;
    const float PIF = 3.14159274101257324f;
    for (int i = tid; i < BLKS; i += 256) {
        int g = F*BLKS + i;
        float c = L0[(size_t)b*LTOT + g];
        if (g >= 16) c = c + L1[(size_t)b*NCH + (g >> 4) - 1];
        float x = c - floorf(c);
        float pix = PIF * x;
        float v;
        if (pix < 1e-8f) v = 1.0f;
        else             v = sinf(af * pix) / (af * sinf(pix));
        hs[(size_t)b*LTOT + g] = v;
    }
}

// ---------------------------------------------------------------------------
// Stage-1 FIR (r17, measured 40 us): 128 threads, R=4, LDS coeff windows,
// wave-uniform global sources.
// ---------------------------------------------------------------------------
__global__ void __launch_bounds__(128) k_mix(const float* __restrict__ hs,
                                             const float* __restrict__ sn,
                                             const float* __restrict__ hks,
                                             const float* __restrict__ nk,
                                             float* __restrict__ mixg) {
    __shared__ float Wh1[1024], Wn1[1024], Wh0[1024], Wn0[1024];
    int F = blockIdx.x, b = blockIdx.y, tid = threadIdx.x;
    const f4* khF4 = (const f4*)(hks + ((size_t)b*NFR + F)*W4);
    const f4* knF4 = (const f4*)(nk  + ((size_t)b*NFR + F)*W4);
    f4 z; z.x = z.y = z.z = z.w = 0.0f;
    for (int i = tid; i < 256; i += 128) {
        ((f4*)Wh1)[i] = (i < 128) ? khF4[i] : z;
        ((f4*)Wn1)[i] = (i < 128) ? knF4[i] : z;
        ((f4*)Wh0)[i] = (i >= 128 && F >= 1) ? khF4[i - 256] : z;  // row F-1
        ((f4*)Wn0)[i] = (i >= 128 && F >= 1) ? knF4[i - 256] : z;
    }
    __syncthreads();
    int j0 = tid * 4;
    float a0=0,a1=0,a2=0,a3=0;
    const float* hsF = hs + (size_t)b*LTOT + (size_t)F*BLKS;
    segmix(Wh1, Wn1, 512 - j0, hsF, sn + (F*BLKS) % SN_LEN, a0,a1,a2,a3);
    if (F >= 1)
        segmix(Wh0, Wn0, 512 - j0, hsF - BLKS, sn + ((F-1)*BLKS) % SN_LEN,
               a0,a1,a2,a3);
    f4 r; r.x=a0; r.y=a1; r.z=a2; r.w=a3;
    *(f4*)(mixg + (size_t)b*LTOT + (size_t)F*BLKS + j0) = r;
}

// ---------------------------------------------------------------------------
// Stage-2 FIR v8: 64 threads (1 wave), R=8. Five zero-padded 1024-float
// coefficient windows, XOR-swizzled in LDS (20 KB); sources via SMEM-uniform
// global loads. Segment order q1,q2,q3,q4,q0 (= r13), taps ascend in m.
// ---------------------------------------------------------------------------
__global__ void __launch_bounds__(64) k_out(const float* __restrict__ mixg,
                                            const float* __restrict__ hk,
                                            float* __restrict__ outp) {
    __shared__ float Wc[5][1024];
    int F = blockIdx.x, b = blockIdx.y, tid = threadIdx.x;
    f4 z; z.x = z.y = z.z = z.w = 0.0f;
    #pragma unroll
    for (int q = 0; q < 5; ++q) {
        int fs = F - 4 + q;
        const f4* row4 = (const f4*)(hk + ((size_t)b*NFR + fs)*WL);
        f4* Wp = (f4*)Wc[q];
        #pragma unroll
        for (int k = 0; k < 4; ++k) {
            int w = tid + 64*k;                 // f4 index 0..255
            f4 v = z;
            if (fs >= 0) {
                if (q == 0)      { if (w >= 128) v = row4[w - 128]; }
                else if (q == 4) { if (w < 128)  v = row4[384 + w]; }
                else             v = row4[128*(q-1) + w];
            }
            Wp[w ^ ((w >> 3) & 1)] = v;         // swizzled store
        }
    }
    __syncthreads();
    int j0 = tid * 8;
    int c0 = 512 - j0;
    float a0=0,a1=0,a2=0,a3=0,a4=0,a5=0,a6=0,a7=0;
    const float* mb = mixg + (size_t)b*LTOT;
    #pragma unroll 1
    for (int q = 1; q <= 3; ++q) {
        int fs = F - 4 + q;
        if (fs < 0) continue;                   // uniform per block
        seg8s(Wc[q], c0, mb + (size_t)fs*BLKS, a0,a1,a2,a3,a4,a5,a6,a7);
    }
    seg8s(Wc[4], c0, mb + (size_t)F*BLKS, a0,a1,a2,a3,a4,a5,a6,a7);
    if (F >= 4)
        seg8s(Wc[0], c0, mb + (size_t)(F-4)*BLKS, a0,a1,a2,a3,a4,a5,a6,a7);
    float* o = outp + (size_t)b*LTOT + (size_t)F*BLKS + j0;
    f4 r0, r1;
    r0.x = fminf(fmaxf(a0, -1.0f), 1.0f);
    r0.y = fminf(fmaxf(a1, -1.0f), 1.0f);
    r0.z = fminf(fmaxf(a2, -1.0f), 1.0f);
    r0.w = fminf(fmaxf(a3, -1.0f), 1.0f);
    r1.x = fminf(fmaxf(a4, -1.0f), 1.0f);
    r1.y = fminf(fmaxf(a5, -1.0f), 1.0f);
    r1.z = fminf(fmaxf(a6, -1.0f), 1.0f);
    r1.w = fminf(fmaxf(a7, -1.0f), 1.0f);
    *(f4*)o = r0; *(f4*)(o + 4) = r1;
}

// ---------------------------------------------------------------------------
extern "C" void kernel_launch(void* const* d_in, const int* in_sizes, int n_in,
                              void* d_out, int out_size, void* d_ws, size_t ws_size,
                              hipStream_t stream) {
    const float* f0  = (const float*)d_in[0];   // (B,NF,1)
    const float* hk  = (const float*)d_in[1];   // (B,NF,2048)
    const float* hks = (const float*)d_in[2];   // (B,NF,512)
    const float* nk  = (const float*)d_in[3];   // (B,NF,512)
    const float* sn  = (const float*)d_in[4];   // (260096,)
    float* outp = (float*)d_out;                // (B,L) f32

    float* ws   = (float*)d_ws;
    float* L0   = ws;                                   // NB*L     = 4 MB
    float* L1   = L0 + (size_t)NB*LTOT;                 // NB*16384 = 256 KB
    float* hsb  = L1 + (size_t)NB*NCH;                  // NB*L     = 4 MB
    float* mixg = hsb + (size_t)NB*LTOT;                // NB*L     = 4 MB

    hipLaunchKernelGGL(k_scan_a, dim3(64, NB),  dim3(256),  0, stream, f0, L0, L1);
    hipLaunchKernelGGL(k_scan_b, dim3(NB),      dim3(1024), 0, stream, L1);
    hipLaunchKernelGGL(k_source, dim3(NFR, NB), dim3(256),  0, stream, f0, L0, L1, hsb);
    hipLaunchKernelGGL(k_mix,    dim3(NFR, NB), dim3(128),  0, stream, hsb, sn, hks, nk, mixg);
    hipLaunchKernelGGL(k_out,    dim3(NFR, NB), dim3(64),   0, stream, mixg, hk, outp);
}

// Round 21
// 173.741 us; speedup vs baseline: 1.0452x; 1.0452x over previous
//
#include <hip/hip_runtime.h>

// FirNeXtV2 DDSP synth. Numerics certified r13-r20 (absmax 0.0078125).
// Perf v9: k_out minimal-LDS hybrid — only the two triangular coefficient
// windows (H4/H0, 8 KB) live in LDS; q1-3 coefficients stream per-lane from
// global (L1); ALL sources via wave-uniform global loads (scalar/broadcast).
// 8 KB LDS -> full 8-block residency, 16 waves/CU cap. k_mix = r17 (40 us).

#define BLKS  512
#define WL    2048
#define W4    512
#define NB    4
#define NFR   512
#define LTOT  (NFR*BLKS)     // 262144
#define NCH   (LTOT/16)      // 16384
#define SN_LEN 260096        // WL*127

typedef float f4 __attribute__((ext_vector_type(4)));

// R=4 x 4 taps; window slides A->B. Per-output taps ascend in m.
static __device__ __forceinline__ void seg4(const float* __restrict__ P, int c0,
                                            const float* __restrict__ S,
                                            float&a0,float&a1,float&a2,float&a3) {
    f4 A = *(const f4*)(P + c0 - 4);
    #pragma unroll 4
    for (int m0 = 0; m0 < 512; m0 += 4) {
        f4 B = *(const f4*)(P + c0 + m0);
        f4 x = *(const f4*)(S + m0);
        a0 += B.x*x.x; a0 += B.y*x.y; a0 += B.z*x.z; a0 += B.w*x.w;
        a1 += A.w*x.x; a1 += B.x*x.y; a1 += B.y*x.z; a1 += B.z*x.w;
        a2 += A.z*x.x; a2 += A.w*x.y; a2 += B.x*x.z; a2 += B.y*x.w;
        a3 += A.y*x.x; a3 += A.z*x.y; a3 += A.w*x.z; a3 += B.x*x.w;
        A = B;
    }
}

// Paired harmonic+noise segment (k_mix), r17 structure.
static __device__ __forceinline__ void segmix(const float* __restrict__ Ph,
                                              const float* __restrict__ Pn, int c0,
                                              const float* __restrict__ Sh,
                                              const float* __restrict__ Sn,
                                              float&a0,float&a1,float&a2,float&a3) {
    f4 Ah = *(const f4*)(Ph + c0 - 4);
    f4 An = *(const f4*)(Pn + c0 - 4);
    #pragma unroll 4
    for (int m0 = 0; m0 < 512; m0 += 4) {
        f4 Bh = *(const f4*)(Ph + c0 + m0);
        f4 Bn = *(const f4*)(Pn + c0 + m0);
        f4 xh = *(const f4*)(Sh + m0);
        f4 xr = *(const f4*)(Sn + m0);
        f4 xn; xn.x = xr.x*0.3162f; xn.y = xr.y*0.3162f;
               xn.z = xr.z*0.3162f; xn.w = xr.w*0.3162f;
        a0 += Bh.x*xh.x; a0 += Bn.x*xn.x;  a0 += Bh.y*xh.y; a0 += Bn.y*xn.y;
        a0 += Bh.z*xh.z; a0 += Bn.z*xn.z;  a0 += Bh.w*xh.w; a0 += Bn.w*xn.w;
        a1 += Ah.w*xh.x; a1 += An.w*xn.x;  a1 += Bh.x*xh.y; a1 += Bn.x*xn.y;
        a1 += Bh.y*xh.z; a1 += Bn.y*xn.z;  a1 += Bh.z*xh.w; a1 += Bn.z*xn.w;
        a2 += Ah.z*xh.x; a2 += An.z*xn.x;  a2 += Ah.w*xh.y; a2 += An.w*xn.y;
        a2 += Bh.x*xh.z; a2 += Bn.x*xn.z;  a2 += Bh.y*xh.w; a2 += Bn.y*xn.w;
        a3 += Ah.y*xh.x; a3 += An.y*xn.x;  a3 += Ah.z*xh.y; a3 += An.z*xn.y;
        a3 += Ah.w*xh.z; a3 += An.w*xn.z;  a3 += Bh.x*xh.w; a3 += Bn.x*xn.w;
        Ah = Bh; An = Bn;
    }
}

// ---------------------------------------------------------------------------
__global__ void __launch_bounds__(256) k_scan_a(const float* __restrict__ f0_frames,
                                                float* __restrict__ L0,
                                                float* __restrict__ L1) {
    int b = blockIdx.y;
    int chunk = blockIdx.x * 256 + threadIdx.x;
    int g0 = chunk * 16;
    float d = f0_frames[b*NFR + (g0 >> 9)] / 44100.0f;
    float* o = L0 + (size_t)b*LTOT + g0;
    float acc = 0.0f;
    #pragma unroll
    for (int j = 0; j < 16; ++j) { acc = acc + d; o[j] = acc; }
    L1[(size_t)b*NCH + chunk] = acc;
}

__global__ void __launch_bounds__(1024) k_scan_b(float* __restrict__ L1g) {
    __shared__ float sL2[1024];
    __shared__ float sL3[64];
    __shared__ float sL4[4];
    int b = blockIdx.x, tid = threadIdx.x;
    float* L1 = L1g + (size_t)b*NCH;
    {
        float* p = L1 + tid*16;
        float acc = 0.0f;
        #pragma unroll
        for (int j = 0; j < 16; ++j) { acc = acc + p[j]; p[j] = acc; }
        sL2[tid] = acc;
    }
    __syncthreads();
    if (tid < 64) {
        float acc = 0.0f;
        #pragma unroll
        for (int j = 0; j < 16; ++j) { acc = acc + sL2[tid*16+j]; sL2[tid*16+j] = acc; }
        sL3[tid] = acc;
    }
    __syncthreads();
    if (tid < 4) {
        float acc = 0.0f;
        #pragma unroll
        for (int j = 0; j < 16; ++j) { acc = acc + sL3[tid*16+j]; sL3[tid*16+j] = acc; }
        sL4[tid] = acc;
    }
    __syncthreads();
    if (tid == 0) {
        float acc = 0.0f;
        #pragma unroll
        for (int j = 0; j < 4; ++j) { acc = acc + sL4[j]; sL4[j] = acc; }
    }
    __syncthreads();
    if (tid >= 16 && tid < 64) sL3[tid] = sL3[tid] + sL4[tid/16 - 1];
    __syncthreads();
    if (tid >= 16) sL2[tid] = sL2[tid] + sL3[tid/16 - 1];
    __syncthreads();
    for (int i = tid; i < NCH; i += 1024)
        if (i >= 16) L1[i] = L1[i] + sL2[i/16 - 1];
}

__global__ void __launch_bounds__(256) k_source(const float* __restrict__ f0_frames,
                                                const float* __restrict__ L0,
                                                const float* __restrict__ L1,
                                                float* __restrict__ hs) {
    int F = blockIdx.x, b = blockIdx.y;
    int tid = threadIdx.x;
    float f0 = f0_frames[b*NFR + F];
    float af = rintf(44100.0f / fmaxf(f0, 20.0f) * 0.5f) * 2.0f + 1.0f;
    const float PIF = 3.14159274101257324f;
    for (int i = tid; i < BLKS; i += 256) {
        int g = F*BLKS + i;
        float c = L0[(size_t)b*LTOT + g];
        if (g >= 16) c = c + L1[(size_t)b*NCH + (g >> 4) - 1];
        float x = c - floorf(c);
        float pix = PIF * x;
        float v;
        if (pix < 1e-8f) v = 1.0f;
        else             v = sinf(af * pix) / (af * sinf(pix));
        hs[(size_t)b*LTOT + g] = v;
    }
}

// ---------------------------------------------------------------------------
// Stage-1 FIR (r17, measured 40 us): 128 threads, R=4, LDS coeff windows,
// wave-uniform global sources.
// ---------------------------------------------------------------------------
__global__ void __launch_bounds__(128) k_mix(const float* __restrict__ hs,
                                             const float* __restrict__ sn,
                                             const float* __restrict__ hks,
                                             const float* __restrict__ nk,
                                             float* __restrict__ mixg) {
    __shared__ float Wh1[1024], Wn1[1024], Wh0[1024], Wn0[1024];
    int F = blockIdx.x, b = blockIdx.y, tid = threadIdx.x;
    const f4* khF4 = (const f4*)(hks + ((size_t)b*NFR + F)*W4);
    const f4* knF4 = (const f4*)(nk  + ((size_t)b*NFR + F)*W4);
    f4 z; z.x = z.y = z.z = z.w = 0.0f;
    for (int i = tid; i < 256; i += 128) {
        ((f4*)Wh1)[i] = (i < 128) ? khF4[i] : z;
        ((f4*)Wn1)[i] = (i < 128) ? knF4[i] : z;
        ((f4*)Wh0)[i] = (i >= 128 && F >= 1) ? khF4[i - 256] : z;  // row F-1
        ((f4*)Wn0)[i] = (i >= 128 && F >= 1) ? knF4[i - 256] : z;
    }
    __syncthreads();
    int j0 = tid * 4;
    float a0=0,a1=0,a2=0,a3=0;
    const float* hsF = hs + (size_t)b*LTOT + (size_t)F*BLKS;
    segmix(Wh1, Wn1, 512 - j0, hsF, sn + (F*BLKS) % SN_LEN, a0,a1,a2,a3);
    if (F >= 1)
        segmix(Wh0, Wn0, 512 - j0, hsF - BLKS, sn + ((F-1)*BLKS) % SN_LEN,
               a0,a1,a2,a3);
    f4 r; r.x=a0; r.y=a1; r.z=a2; r.w=a3;
    *(f4*)(mixg + (size_t)b*LTOT + (size_t)F*BLKS + j0) = r;
}

// ---------------------------------------------------------------------------
// Stage-2 FIR v9: 128 threads, R=4. LDS = ONLY the two triangular coefficient
// windows H4/H0 (8 KB). q1-3 coeffs per-lane from global (L1); all sources
// wave-uniform global loads. Segment order q1,q2,q3,q4,q0 (= r13).
// ---------------------------------------------------------------------------
__global__ void __launch_bounds__(128) k_out(const float* __restrict__ mixg,
                                             const float* __restrict__ hk,
                                             float* __restrict__ outp) {
    __shared__ float H4[1024];     // hk row F [1536..2048), zeros above
    __shared__ float H0[1024];     // zeros below, hk row F-4 [0..512) above
    int F = blockIdx.x, b = blockIdx.y, tid = threadIdx.x;
    f4 z; z.x = z.y = z.z = z.w = 0.0f;
    const f4* rF4 = (const f4*)(hk + ((size_t)b*NFR + F)*WL);
    for (int i4 = tid; i4 < 256; i4 += 128)
        ((f4*)H4)[i4] = (i4 < 128) ? rF4[384 + i4] : z;
    {
        const f4* rA4 = (const f4*)(hk + ((size_t)b*NFR + F - 4)*WL);
        for (int i4 = tid; i4 < 256; i4 += 128) {
            f4 v = z;
            if (i4 >= 128 && F >= 4) v = rA4[i4 - 128];
            ((f4*)H0)[i4] = v;
        }
    }
    __syncthreads();
    int j0 = tid * 4;
    float a0=0,a1=0,a2=0,a3=0;
    const float* mb = mixg + (size_t)b*LTOT;
    #pragma unroll 1
    for (int q = 1; q <= 3; ++q) {
        int fs = F - 4 + q;
        if (fs < 0) continue;                         // uniform per block
        const float* P = hk + ((size_t)b*NFR + fs)*WL;
        seg4(P, 512*q - j0, mb + (size_t)fs*BLKS, a0,a1,a2,a3);
    }
    seg4(H4, 512 - j0, mb + (size_t)F*BLKS, a0,a1,a2,a3);      // row F
    if (F >= 4)
        seg4(H0 + 512, -j0, mb + (size_t)(F-4)*BLKS, a0,a1,a2,a3); // row F-4
    f4 r;
    r.x = fminf(fmaxf(a0, -1.0f), 1.0f);
    r.y = fminf(fmaxf(a1, -1.0f), 1.0f);
    r.z = fminf(fmaxf(a2, -1.0f), 1.0f);
    r.w = fminf(fmaxf(a3, -1.0f), 1.0f);
    *(f4*)(outp + (size_t)b*LTOT + (size_t)F*BLKS + j0) = r;
}

// ---------------------------------------------------------------------------
extern "C" void kernel_launch(void* const* d_in, const int* in_sizes, int n_in,
                              void* d_out, int out_size, void* d_ws, size_t ws_size,
                              hipStream_t stream) {
    const float* f0  = (const float*)d_in[0];   // (B,NF,1)
    const float* hk  = (const float*)d_in[1];   // (B,NF,2048)
    const float* hks = (const float*)d_in[2];   // (B,NF,512)
    const float* nk  = (const float*)d_in[3];   // (B,NF,512)
    const float* sn  = (const float*)d_in[4];   // (260096,)
    float* outp = (float*)d_out;                // (B,L) f32

    float* ws   = (float*)d_ws;
    float* L0   = ws;                                   // NB*L     = 4 MB
    float* L1   = L0 + (size_t)NB*LTOT;                 // NB*16384 = 256 KB
    float* hsb  = L1 + (size_t)NB*NCH;                  // NB*L     = 4 MB
    float* mixg = hsb + (size_t)NB*LTOT;                // NB*L     = 4 MB

    hipLaunchKernelGGL(k_scan_a, dim3(64, NB),  dim3(256),  0, stream, f0, L0, L1);
    hipLaunchKernelGGL(k_scan_b, dim3(NB),      dim3(1024), 0, stream, L1);
    hipLaunchKernelGGL(k_source, dim3(NFR, NB), dim3(256),  0, stream, f0, L0, L1, hsb);
    hipLaunchKernelGGL(k_mix,    dim3(NFR, NB), dim3(128),  0, stream, hsb, sn, hks, nk, mixg);
    hipLaunchKernelGGL(k_out,    dim3(NFR, NB), dim3(128),  0, stream, mixg, hk, outp);
}